// Round 6
// baseline (42.029 us; speedup 1.0000x reference)
//
#include <hip/hip_runtime.h>

#define N_NODES 4096
#define IN_DIM  128
#define OUT_DIM 32
#define HEADS   4
#define FDIM    128   // OUT_DIM*HEADS
#define K1_ROWS 8

// ---------------- Kernel 1: projection + FOLDED attention weights ----------------
// s_i cancels in softmax over j. Weights depend only on j:
//   E[j][h] = exp(s_j[j][h]*scale)   (values ~[0.6,1.7] for this input dist;
//                                     no max-sub needed in f32 -- validated r5)
//   Y[j][c] = E[j][c>>5] * xp[j][c]
// Then out[i] = (sum_{j in N(i)} Y[j]) / (sum_{j in N(i)} E[j]) -- pure sparse sum.
__global__ __launch_bounds__(256) void gat_proj(const float* __restrict__ x,
                                                const float* __restrict__ W,
                                                const float* __restrict__ a,
                                                float* __restrict__ Y,
                                                float* __restrict__ Eg) {
    __shared__ float xs[K1_ROWS * IN_DIM];   // 4 KB: x tile, then reused as xp tile
    __shared__ float eS[K1_ROWS][HEADS];
    const int t    = threadIdx.x;
    const int row0 = blockIdx.x * K1_ROWS;

    ((float4*)xs)[t] = ((const float4*)(x + (size_t)row0 * IN_DIM))[t];
    __syncthreads();

    const int c  = t & 127;          // output column
    const int rg = t >> 7;           // 0..1 -> rows rg*4 .. rg*4+3
    const float* xb = xs + (rg * 4) * IN_DIM;

    float acc0 = 0.f, acc1 = 0.f, acc2 = 0.f, acc3 = 0.f;
#pragma unroll 4
    for (int k0 = 0; k0 < IN_DIM; k0 += 4) {
        const float w0 = W[(k0 + 0) * FDIM + c];
        const float w1 = W[(k0 + 1) * FDIM + c];
        const float w2 = W[(k0 + 2) * FDIM + c];
        const float w3 = W[(k0 + 3) * FDIM + c];
        const float4 x0 = *(const float4*)(xb + 0 * IN_DIM + k0);
        const float4 x1 = *(const float4*)(xb + 1 * IN_DIM + k0);
        const float4 x2 = *(const float4*)(xb + 2 * IN_DIM + k0);
        const float4 x3 = *(const float4*)(xb + 3 * IN_DIM + k0);
        acc0 = fmaf(x0.x, w0, fmaf(x0.y, w1, fmaf(x0.z, w2, fmaf(x0.w, w3, acc0))));
        acc1 = fmaf(x1.x, w0, fmaf(x1.y, w1, fmaf(x1.z, w2, fmaf(x1.w, w3, acc1))));
        acc2 = fmaf(x2.x, w0, fmaf(x2.y, w1, fmaf(x2.z, w2, fmaf(x2.w, w3, acc2))));
        acc3 = fmaf(x3.x, w0, fmaf(x3.y, w1, fmaf(x3.z, w2, fmaf(x3.w, w3, acc3))));
    }

    const int rb = rg * 4;
    __syncthreads();                      // everyone done reading x tile
    xs[(rb + 0) * FDIM + c] = acc0;       // reuse LDS as xp tile
    xs[(rb + 1) * FDIM + c] = acc1;
    xs[(rb + 2) * FDIM + c] = acc2;
    xs[(rb + 3) * FDIM + c] = acc3;
    __syncthreads();

    if (t < K1_ROWS * HEADS) {            // 32 threads: (row, head) pairs
        const int r = t >> 2, h = t & 3;
        const float4* xr = (const float4*)(xs + r * FDIM + h * OUT_DIM);
        const float4* aj = (const float4*)a;             // a[:32]
        float vj = 0.f;
#pragma unroll
        for (int q = 0; q < 8; ++q) {
            const float4 xv = xr[q], a0 = aj[q];
            vj += xv.x * a0.x + xv.y * a0.y + xv.z * a0.z + xv.w * a0.w;
        }
        const float e = __expf(vj * 0.17677669529663687f);   // 1/sqrt(32)
        eS[r][h] = e;
        Eg[(row0 + r) * HEADS + h] = e;
    }
    __syncthreads();

    const int h = c >> 5;                 // head of this column
    Y[(size_t)(row0 + rb + 0) * FDIM + c] = acc0 * eS[rb + 0][h];
    Y[(size_t)(row0 + rb + 1) * FDIM + c] = acc1 * eS[rb + 1][h];
    Y[(size_t)(row0 + rb + 2) * FDIM + c] = acc2 * eS[rb + 2][h];
    Y[(size_t)(row0 + rb + 3) * FDIM + c] = acc3 * eS[rb + 3][h];
}

// ---------------- Kernel 2: wave-per-row ballot-extract sparse sum ----------------
// One WAVE per row. Zero barriers, zero LDS, zero shuffle reduces, no capacity
// limit (scalar mask extraction handles any edge count -> no fallback needed).
// All 16 row-loads issued up front; per-CU 16 waves x 16 KB in flight -> HBM
// stays saturated for the whole kernel.
__global__ __launch_bounds__(256, 4) void gat_sum(const float* __restrict__ adj,
                                                  const float* __restrict__ Y,
                                                  const float* __restrict__ E,
                                                  float* __restrict__ out) {
    const int tid  = threadIdx.x;
    const int lane = tid & 63;
    const int row  = blockIdx.x * 4 + (tid >> 6);   // wave = row
    const int hm   = lane >> 4;                     // head of dims (2*lane, 2*lane+1)

    // ---- load entire adj row: 16 independent dwordx4, all in flight ----
    const float4* arow = (const float4*)(adj + (size_t)row * N_NODES);
    float4 v[16];
#pragma unroll
    for (int c = 0; c < 16; ++c) v[c] = arow[c * 64 + lane];

    const float2* Y2 = (const float2*)Y;
    const float*  Eh = E + hm;                      // E[j][hm] = Eh[j*4]
    float ax = 0.f, ay = 0.f, z = 0.f;

    // ---- ballot-extract edges; j is SCALAR (s_ff1) -> wave-uniform loads ----
    // element c,lane of float4 covers columns c*256 + lane*4 + m; set-bit b in
    // the component-m ballot mask => column j = c*256 + b*4 + m.
#pragma unroll
    for (int c = 0; c < 16; ++c) {
#pragma unroll
        for (int m = 0; m < 4; ++m) {
            const float val = (m == 0) ? v[c].x : (m == 1) ? v[c].y
                            : (m == 2) ? v[c].z : v[c].w;
            unsigned long long mask = __ballot(val != 0.f);
            while (mask) {
                const int b = __builtin_ctzll(mask);
                mask &= mask - 1ULL;
                const int j = c * 256 + b * 4 + m;
                const float  e = Eh[(size_t)j * HEADS];            // 1 line/wave
                const float2 y = Y2[(size_t)j * 64 + lane];        // 512B coalesced
                z  += e;
                ax += y.x;
                ay += y.y;
            }
        }
    }

    const float invZ = 1.0f / z;   // z >= E[row][hm] > 0 (diagonal)
    float2 o;
    o.x = ax * invZ;
    o.y = ay * invZ;
    ((float2*)out)[(size_t)row * 64 + lane] = o;
}

extern "C" void kernel_launch(void* const* d_in, const int* in_sizes, int n_in,
                              void* d_out, int out_size, void* d_ws, size_t ws_size,
                              hipStream_t stream) {
    const float* x   = (const float*)d_in[0];
    const float* adj = (const float*)d_in[1];
    const float* W   = (const float*)d_in[2];
    const float* a   = (const float*)d_in[3];
    float* out = (float*)d_out;

    float* Y = (float*)d_ws;                     // 4096*128 f32 = 2 MB
    float* E = Y + (size_t)N_NODES * FDIM;       // 4096*4 f32 = 64 KB

    gat_proj<<<N_NODES / K1_ROWS, 256, 0, stream>>>(x, W, a, Y, E);
    gat_sum<<<N_NODES / 4, 256, 0, stream>>>(adj, Y, E, out);
}

// Round 7
// 33.565 us; speedup vs baseline: 1.2521x; 1.2521x over previous
//
#include <hip/hip_runtime.h>

#define N_NODES 4096
#define IN_DIM  128
#define OUT_DIM 32
#define HEADS   4
#define FDIM    128   // OUT_DIM*HEADS
#define K1_ROWS 8

// ---------------- Kernel 1: projection + FOLDED attention weights ----------------
// s_i cancels in softmax over j. Weights depend only on j:
//   E[j][h] = exp(s_j[j][h]*scale)   (~[0.6,1.7] for this input dist; no max-sub
//                                     needed in f32 -- validated rounds 5/6)
//   Y[j][c] = E[j][c>>5] * xp[j][c]
// Then out[i] = (sum_{j in N(i)} Y[j]) / (sum_{j in N(i)} E[j]) -- pure sparse sum.
__global__ __launch_bounds__(256) void gat_proj(const float* __restrict__ x,
                                                const float* __restrict__ W,
                                                const float* __restrict__ a,
                                                float* __restrict__ Y,
                                                float* __restrict__ Eg) {
    __shared__ float xs[K1_ROWS * IN_DIM];   // 4 KB: x tile, then reused as xp tile
    __shared__ float eS[K1_ROWS][HEADS];
    const int t    = threadIdx.x;
    const int row0 = blockIdx.x * K1_ROWS;

    ((float4*)xs)[t] = ((const float4*)(x + (size_t)row0 * IN_DIM))[t];
    __syncthreads();

    const int c  = t & 127;          // output column
    const int rg = t >> 7;           // 0..1 -> rows rg*4 .. rg*4+3
    const float* xb = xs + (rg * 4) * IN_DIM;

    float acc0 = 0.f, acc1 = 0.f, acc2 = 0.f, acc3 = 0.f;
#pragma unroll 4
    for (int k0 = 0; k0 < IN_DIM; k0 += 4) {
        const float w0 = W[(k0 + 0) * FDIM + c];
        const float w1 = W[(k0 + 1) * FDIM + c];
        const float w2 = W[(k0 + 2) * FDIM + c];
        const float w3 = W[(k0 + 3) * FDIM + c];
        const float4 x0 = *(const float4*)(xb + 0 * IN_DIM + k0);
        const float4 x1 = *(const float4*)(xb + 1 * IN_DIM + k0);
        const float4 x2 = *(const float4*)(xb + 2 * IN_DIM + k0);
        const float4 x3 = *(const float4*)(xb + 3 * IN_DIM + k0);
        acc0 = fmaf(x0.x, w0, fmaf(x0.y, w1, fmaf(x0.z, w2, fmaf(x0.w, w3, acc0))));
        acc1 = fmaf(x1.x, w0, fmaf(x1.y, w1, fmaf(x1.z, w2, fmaf(x1.w, w3, acc1))));
        acc2 = fmaf(x2.x, w0, fmaf(x2.y, w1, fmaf(x2.z, w2, fmaf(x2.w, w3, acc2))));
        acc3 = fmaf(x3.x, w0, fmaf(x3.y, w1, fmaf(x3.z, w2, fmaf(x3.w, w3, acc3))));
    }

    const int rb = rg * 4;
    __syncthreads();                      // everyone done reading x tile
    xs[(rb + 0) * FDIM + c] = acc0;       // reuse LDS as xp tile
    xs[(rb + 1) * FDIM + c] = acc1;
    xs[(rb + 2) * FDIM + c] = acc2;
    xs[(rb + 3) * FDIM + c] = acc3;
    __syncthreads();

    if (t < K1_ROWS * HEADS) {            // 32 threads: (row, head) pairs
        const int r = t >> 2, h = t & 3;
        const float4* xr = (const float4*)(xs + r * FDIM + h * OUT_DIM);
        const float4* aj = (const float4*)a;             // a[:32]
        float vj = 0.f;
#pragma unroll
        for (int q = 0; q < 8; ++q) {
            const float4 xv = xr[q], a0 = aj[q];
            vj += xv.x * a0.x + xv.y * a0.y + xv.z * a0.z + xv.w * a0.w;
        }
        const float e = __expf(vj * 0.17677669529663687f);   // 1/sqrt(32)
        eS[r][h] = e;
        Eg[(row0 + r) * HEADS + h] = e;
    }
    __syncthreads();

    const int h = c >> 5;                 // head of this column
    Y[(size_t)(row0 + rb + 0) * FDIM + c] = acc0 * eS[rb + 0][h];
    Y[(size_t)(row0 + rb + 1) * FDIM + c] = acc1 * eS[rb + 1][h];
    Y[(size_t)(row0 + rb + 2) * FDIM + c] = acc2 * eS[rb + 2][h];
    Y[(size_t)(row0 + rb + 3) * FDIM + c] = acc3 * eS[rb + 3][h];
}

// ---------------- Kernel 2: wave-per-row, compaction + 8-deep batched gather ----
// One WAVE per row, zero barriers (LDS list is wave-private), no capacity
// fallback (1024 = full row). Phase 1: ballot+popcount compaction into LDS.
// Phase 2: 8 edges per iteration -- two broadcast int4 ds_reads, then 8
// independent E + 8 independent Y loads in flight, 4 separate acc chains.
__global__ __launch_bounds__(256, 4) void gat_sum(const float* __restrict__ adj,
                                                  const float* __restrict__ Y,
                                                  const float* __restrict__ E,
                                                  float* __restrict__ out) {
    const int tid  = threadIdx.x;
    const int wv   = tid >> 6;
    const int lane = tid & 63;
    const int row  = blockIdx.x * 4 + wv;           // wave = row
    const int hm   = lane >> 4;                     // head of dims (2*lane, 2*lane+1)

    __shared__ int elist[4][N_NODES / 4];           // 16 KB, wave-private segments
    int* seg = elist[wv];

    // ---- Phase 1: load entire adj row (16 x 1KB coalesced), compact to LDS ----
    const float4* arow = (const float4*)(adj + (size_t)row * N_NODES);
    float4 v[16];
#pragma unroll
    for (int c = 0; c < 16; ++c) v[c] = arow[c * 64 + lane];

    const unsigned long long lt = (1ULL << lane) - 1ULL;
    int base = 0;
#pragma unroll
    for (int c = 0; c < 16; ++c) {
        const int cb = c * 256 + lane * 4;
        const float vals[4] = {v[c].x, v[c].y, v[c].z, v[c].w};
#pragma unroll
        for (int m = 0; m < 4; ++m) {
            const unsigned long long mk = __ballot(vals[m] != 0.f);
            if (vals[m] != 0.f) seg[base + __popcll(mk & lt)] = cb + m;
            base += __popcll(mk);   // wave-uniform
        }
    }
    const int cnt = base;

    // ---- Phase 2: batched gather-sum, 8 edges (16 loads) in flight ----
    const float2* Y2 = (const float2*)Y;
    const float*  Eh = E + hm;                      // E[j][hm] = Eh[j*4]
    float ax0 = 0.f, ay0 = 0.f, z0 = 0.f;
    float ax1 = 0.f, ay1 = 0.f, z1 = 0.f;
    float ax2 = 0.f, ay2 = 0.f, z2 = 0.f;
    float ax3 = 0.f, ay3 = 0.f, z3 = 0.f;

    int e = 0;
    for (; e + 8 <= cnt; e += 8) {
        const int4 ja = *(const int4*)&seg[e];      // broadcast ds_read_b128
        const int4 jb = *(const int4*)&seg[e + 4];
        const float2 y0 = Y2[(size_t)ja.x * 64 + lane];
        const float2 y1 = Y2[(size_t)ja.y * 64 + lane];
        const float2 y2 = Y2[(size_t)ja.z * 64 + lane];
        const float2 y3 = Y2[(size_t)ja.w * 64 + lane];
        const float2 y4 = Y2[(size_t)jb.x * 64 + lane];
        const float2 y5 = Y2[(size_t)jb.y * 64 + lane];
        const float2 y6 = Y2[(size_t)jb.z * 64 + lane];
        const float2 y7 = Y2[(size_t)jb.w * 64 + lane];
        const float e0 = Eh[(size_t)ja.x * 4];
        const float e1 = Eh[(size_t)ja.y * 4];
        const float e2 = Eh[(size_t)ja.z * 4];
        const float e3 = Eh[(size_t)ja.w * 4];
        const float e4 = Eh[(size_t)jb.x * 4];
        const float e5 = Eh[(size_t)jb.y * 4];
        const float e6 = Eh[(size_t)jb.z * 4];
        const float e7 = Eh[(size_t)jb.w * 4];
        ax0 += y0.x; ay0 += y0.y; z0 += e0;
        ax1 += y1.x; ay1 += y1.y; z1 += e1;
        ax2 += y2.x; ay2 += y2.y; z2 += e2;
        ax3 += y3.x; ay3 += y3.y; z3 += e3;
        ax0 += y4.x; ay0 += y4.y; z0 += e4;
        ax1 += y5.x; ay1 += y5.y; z1 += e5;
        ax2 += y6.x; ay2 += y6.y; z2 += e6;
        ax3 += y7.x; ay3 += y7.y; z3 += e7;
    }
    for (; e < cnt; ++e) {                          // tail (<= 7 edges)
        const int j = seg[e];
        const float2 yv = Y2[(size_t)j * 64 + lane];
        ax0 += yv.x; ay0 += yv.y; z0 += Eh[(size_t)j * 4];
    }

    const float z = (z0 + z1) + (z2 + z3);          // z > 0 (diagonal edge)
    const float invZ = 1.0f / z;
    float2 o;
    o.x = ((ax0 + ax1) + (ax2 + ax3)) * invZ;
    o.y = ((ay0 + ay1) + (ay2 + ay3)) * invZ;
    ((float2*)out)[(size_t)row * 64 + lane] = o;
}

extern "C" void kernel_launch(void* const* d_in, const int* in_sizes, int n_in,
                              void* d_out, int out_size, void* d_ws, size_t ws_size,
                              hipStream_t stream) {
    const float* x   = (const float*)d_in[0];
    const float* adj = (const float*)d_in[1];
    const float* W   = (const float*)d_in[2];
    const float* a   = (const float*)d_in[3];
    float* out = (float*)d_out;

    float* Y = (float*)d_ws;                     // 4096*128 f32 = 2 MB
    float* E = Y + (size_t)N_NODES * FDIM;       // 4096*4 f32 = 64 KB

    gat_proj<<<N_NODES / K1_ROWS, 256, 0, stream>>>(x, W, a, Y, E);
    gat_sum<<<N_NODES / 4, 256, 0, stream>>>(adj, Y, E, out);
}

// Round 8
// 29.473 us; speedup vs baseline: 1.4260x; 1.1388x over previous
//
#include <hip/hip_runtime.h>

#define N_NODES 4096
#define IN_DIM  128
#define OUT_DIM 32
#define HEADS   4
#define FDIM    128   // OUT_DIM*HEADS
#define K1_ROWS 8
#define CAP     512   // per-HALF-row compacted capacity (mean 30.7; exact fallback)

// RNE float->bf16 pack of two values into one dword (lo = a, hi = b)
static __device__ __forceinline__ unsigned bf16pack(float a, float b) {
    unsigned ua = __float_as_uint(a), ub = __float_as_uint(b);
    ua = (ua + 0x7FFFu + ((ua >> 16) & 1u)) >> 16;
    ub = (ub + 0x7FFFu + ((ub >> 16) & 1u)) >> 16;
    return ua | (ub << 16);
}

// ---------------- Kernel 1: projection + folded weights -> packed bf16 Y ----------
// s_i cancels in softmax over j (validated r5-r7). Weights depend only on j:
//   E[j][h] = exp(s_j[j][h]*scale); Ybf[j][c] = bf16(E[j][c>>5] * xp[j][c])
// out[i] = (sum_edges Ybf[j]) / (sum_edges E[j]) -- pure sparse sum, f32 accum.
__global__ __launch_bounds__(256) void gat_proj(const float* __restrict__ x,
                                                const float* __restrict__ W,
                                                const float* __restrict__ a,
                                                unsigned* __restrict__ Ybf,
                                                float* __restrict__ Eg) {
    __shared__ float xs[K1_ROWS * IN_DIM];   // 4 KB: x tile, then reused as xp tile
    __shared__ float eS[K1_ROWS][HEADS];
    const int t    = threadIdx.x;
    const int row0 = blockIdx.x * K1_ROWS;

    ((float4*)xs)[t] = ((const float4*)(x + (size_t)row0 * IN_DIM))[t];
    __syncthreads();

    const int c  = t & 127;          // output column
    const int rg = t >> 7;           // 0..1 -> rows rg*4 .. rg*4+3
    const float* xb = xs + (rg * 4) * IN_DIM;

    float acc0 = 0.f, acc1 = 0.f, acc2 = 0.f, acc3 = 0.f;
#pragma unroll 4
    for (int k0 = 0; k0 < IN_DIM; k0 += 4) {
        const float w0 = W[(k0 + 0) * FDIM + c];
        const float w1 = W[(k0 + 1) * FDIM + c];
        const float w2 = W[(k0 + 2) * FDIM + c];
        const float w3 = W[(k0 + 3) * FDIM + c];
        const float4 x0 = *(const float4*)(xb + 0 * IN_DIM + k0);
        const float4 x1 = *(const float4*)(xb + 1 * IN_DIM + k0);
        const float4 x2 = *(const float4*)(xb + 2 * IN_DIM + k0);
        const float4 x3 = *(const float4*)(xb + 3 * IN_DIM + k0);
        acc0 = fmaf(x0.x, w0, fmaf(x0.y, w1, fmaf(x0.z, w2, fmaf(x0.w, w3, acc0))));
        acc1 = fmaf(x1.x, w0, fmaf(x1.y, w1, fmaf(x1.z, w2, fmaf(x1.w, w3, acc1))));
        acc2 = fmaf(x2.x, w0, fmaf(x2.y, w1, fmaf(x2.z, w2, fmaf(x2.w, w3, acc2))));
        acc3 = fmaf(x3.x, w0, fmaf(x3.y, w1, fmaf(x3.z, w2, fmaf(x3.w, w3, acc3))));
    }

    const int rb = rg * 4;
    __syncthreads();                      // everyone done reading x tile
    xs[(rb + 0) * FDIM + c] = acc0;       // reuse LDS as xp tile
    xs[(rb + 1) * FDIM + c] = acc1;
    xs[(rb + 2) * FDIM + c] = acc2;
    xs[(rb + 3) * FDIM + c] = acc3;
    __syncthreads();

    if (t < K1_ROWS * HEADS) {            // 32 threads: (row, head) pairs
        const int r = t >> 2, h = t & 3;
        const float4* xr = (const float4*)(xs + r * FDIM + h * OUT_DIM);
        const float4* aj = (const float4*)a;             // a[:32]
        float vj = 0.f;
#pragma unroll
        for (int q = 0; q < 8; ++q) {
            const float4 xv = xr[q], a0 = aj[q];
            vj += xv.x * a0.x + xv.y * a0.y + xv.z * a0.z + xv.w * a0.w;
        }
        const float e = __expf(vj * 0.17677669529663687f);   // 1/sqrt(32)
        eS[r][h] = e;
        Eg[(row0 + r) * HEADS + h] = e;
    }
    __syncthreads();

    // pack Ybf tile: 8 rows x 64 dwords (2 bf16 cols per dword)
#pragma unroll
    for (int q = 0; q < 2; ++q) {
        const int idx = t + 256 * q;          // 0..511
        const int r   = idx >> 6;
        const int cp  = idx & 63;             // dword index = dims (2cp, 2cp+1)
        const float e = eS[r][cp >> 4];
        const float a0 = xs[r * FDIM + 2 * cp]     * e;
        const float a1 = xs[r * FDIM + 2 * cp + 1] * e;
        Ybf[(size_t)(row0 + r) * 64 + cp] = bf16pack(a0, a1);
    }
}

// ---------------- Kernel 2: 2 waves/row, compaction + ILP-16 bf16 gather ---------
// Wave pair (2k, 2k+1) handles one row; each wave scans HALF the adj row,
// compacts to its own LDS segment (no barrier needed), gathers packed-bf16 Y
// rows 16-deep, combines via one __syncthreads + LDS.
__global__ __launch_bounds__(256, 6) void gat_sum(const float* __restrict__ adj,
                                                  const unsigned* __restrict__ Ybf,
                                                  const float* __restrict__ E,
                                                  float* __restrict__ out) {
    const int tid  = threadIdx.x;
    const int wv   = tid >> 6;
    const int lane = tid & 63;
    const int row  = blockIdx.x * 2 + (wv >> 1);
    const int half = wv & 1;
    const int hm   = lane >> 4;                 // head of dims (2*lane, 2*lane+1)

    __shared__ int    seg_s[4][CAP];            // 8 KB
    __shared__ float4 part_s[4][64];            // 4 KB: {ax, ay, z, -}

    // ---- Phase 1: load half-row (8 KB coalesced), ballot-compact to LDS ----
    const float4* arow = (const float4*)(adj + (size_t)row * N_NODES) + half * 512;
    float4 v[8];
#pragma unroll
    for (int c = 0; c < 8; ++c) v[c] = arow[c * 64 + lane];

    const unsigned long long lt = (1ULL << lane) - 1ULL;
    int* seg = seg_s[wv];
    int base = 0;
#pragma unroll
    for (int c = 0; c < 8; ++c) {
        const int cb = half * 2048 + c * 256 + lane * 4;
        const float vals[4] = {v[c].x, v[c].y, v[c].z, v[c].w};
#pragma unroll
        for (int m = 0; m < 4; ++m) {
            const unsigned long long mk = __ballot(vals[m] != 0.f);
            const int pos = base + __popcll(mk & lt);
            if (vals[m] != 0.f && pos < CAP) seg[pos] = cb + m;
            base += __popcll(mk);   // wave-uniform
        }
    }
    const int cnt = base;

    const float* Eh = E + hm;                   // E[j][hm] = Eh[j*4]
    float ax0 = 0.f, ay0 = 0.f, z0 = 0.f;
    float ax1 = 0.f, ay1 = 0.f, z1 = 0.f;
    float ax2 = 0.f, ay2 = 0.f, z2 = 0.f;
    float ax3 = 0.f, ay3 = 0.f, z3 = 0.f;

#define ACC(ch, u, ev)                                                        \
    {                                                                         \
        ax##ch += __uint_as_float((u) << 16);                                 \
        ay##ch += __uint_as_float((u) & 0xFFFF0000u);                         \
        z##ch  += (ev);                                                       \
    }

    if (__builtin_expect(cnt <= CAP, 1)) {
        // ---- Phase 2: ILP-16 batched gather (16 Y + 16 E loads in flight) ----
        int e = 0;
        for (; e + 16 <= cnt; e += 16) {
            const int4 ja = *(const int4*)&seg[e];
            const int4 jb = *(const int4*)&seg[e + 4];
            const int4 jc = *(const int4*)&seg[e + 8];
            const int4 jd = *(const int4*)&seg[e + 12];
            const unsigned u0  = Ybf[(size_t)ja.x * 64 + lane];
            const unsigned u1  = Ybf[(size_t)ja.y * 64 + lane];
            const unsigned u2  = Ybf[(size_t)ja.z * 64 + lane];
            const unsigned u3  = Ybf[(size_t)ja.w * 64 + lane];
            const unsigned u4  = Ybf[(size_t)jb.x * 64 + lane];
            const unsigned u5  = Ybf[(size_t)jb.y * 64 + lane];
            const unsigned u6  = Ybf[(size_t)jb.z * 64 + lane];
            const unsigned u7  = Ybf[(size_t)jb.w * 64 + lane];
            const unsigned u8  = Ybf[(size_t)jc.x * 64 + lane];
            const unsigned u9  = Ybf[(size_t)jc.y * 64 + lane];
            const unsigned u10 = Ybf[(size_t)jc.z * 64 + lane];
            const unsigned u11 = Ybf[(size_t)jc.w * 64 + lane];
            const unsigned u12 = Ybf[(size_t)jd.x * 64 + lane];
            const unsigned u13 = Ybf[(size_t)jd.y * 64 + lane];
            const unsigned u14 = Ybf[(size_t)jd.z * 64 + lane];
            const unsigned u15 = Ybf[(size_t)jd.w * 64 + lane];
            const float e0  = Eh[(size_t)ja.x * 4];
            const float e1  = Eh[(size_t)ja.y * 4];
            const float e2  = Eh[(size_t)ja.z * 4];
            const float e3  = Eh[(size_t)ja.w * 4];
            const float e4  = Eh[(size_t)jb.x * 4];
            const float e5  = Eh[(size_t)jb.y * 4];
            const float e6  = Eh[(size_t)jb.z * 4];
            const float e7  = Eh[(size_t)jb.w * 4];
            const float e8  = Eh[(size_t)jc.x * 4];
            const float e9  = Eh[(size_t)jc.y * 4];
            const float e10 = Eh[(size_t)jc.z * 4];
            const float e11 = Eh[(size_t)jc.w * 4];
            const float e12 = Eh[(size_t)jd.x * 4];
            const float e13 = Eh[(size_t)jd.y * 4];
            const float e14 = Eh[(size_t)jd.z * 4];
            const float e15 = Eh[(size_t)jd.w * 4];
            ACC(0, u0,  e0)  ACC(1, u1,  e1)  ACC(2, u2,  e2)  ACC(3, u3,  e3)
            ACC(0, u4,  e4)  ACC(1, u5,  e5)  ACC(2, u6,  e6)  ACC(3, u7,  e7)
            ACC(0, u8,  e8)  ACC(1, u9,  e9)  ACC(2, u10, e10) ACC(3, u11, e11)
            ACC(0, u12, e12) ACC(1, u13, e13) ACC(2, u14, e14) ACC(3, u15, e15)
        }
        for (; e + 4 <= cnt; e += 4) {
            const int4 ja = *(const int4*)&seg[e];
            const unsigned u0 = Ybf[(size_t)ja.x * 64 + lane];
            const unsigned u1 = Ybf[(size_t)ja.y * 64 + lane];
            const unsigned u2 = Ybf[(size_t)ja.z * 64 + lane];
            const unsigned u3 = Ybf[(size_t)ja.w * 64 + lane];
            const float e0 = Eh[(size_t)ja.x * 4];
            const float e1 = Eh[(size_t)ja.y * 4];
            const float e2 = Eh[(size_t)ja.z * 4];
            const float e3 = Eh[(size_t)ja.w * 4];
            ACC(0, u0, e0) ACC(1, u1, e1) ACC(2, u2, e2) ACC(3, u3, e3)
        }
        for (; e < cnt; ++e) {
            const int j = seg[e];
            const unsigned u = Ybf[(size_t)j * 64 + lane];
            ACC(0, u, Eh[(size_t)j * 4])
        }
    } else {
        // ---- exact fallback (statistically unreachable): replay from registers ----
#pragma unroll
        for (int c = 0; c < 8; ++c) {
            const float vals[4] = {v[c].x, v[c].y, v[c].z, v[c].w};
#pragma unroll
            for (int m = 0; m < 4; ++m) {
                unsigned long long mask = __ballot(vals[m] != 0.f);
                while (mask) {
                    const int b = __builtin_ctzll(mask);
                    mask &= mask - 1ULL;
                    const int j = half * 2048 + c * 256 + b * 4 + m;
                    const unsigned u = Ybf[(size_t)j * 64 + lane];
                    ACC(0, u, Eh[(size_t)j * 4])
                }
            }
        }
    }
#undef ACC

    part_s[wv][lane] = make_float4((ax0 + ax1) + (ax2 + ax3),
                                   (ay0 + ay1) + (ay2 + ay3),
                                   (z0 + z1) + (z2 + z3), 0.f);
    __syncthreads();

    if ((wv & 1) == 0) {                        // waves 0,2 finalize their row
        const float4 pa = part_s[wv][lane];
        const float4 pb = part_s[wv + 1][lane];
        const float invZ = 1.0f / (pa.z + pb.z);   // > 0 (diagonal edge)
        float2 o;
        o.x = (pa.x + pb.x) * invZ;
        o.y = (pa.y + pb.y) * invZ;
        ((float2*)out)[(size_t)row * 64 + lane] = o;
    }
}

extern "C" void kernel_launch(void* const* d_in, const int* in_sizes, int n_in,
                              void* d_out, int out_size, void* d_ws, size_t ws_size,
                              hipStream_t stream) {
    const float* x   = (const float*)d_in[0];
    const float* adj = (const float*)d_in[1];
    const float* W   = (const float*)d_in[2];
    const float* a   = (const float*)d_in[3];
    float* out = (float*)d_out;

    unsigned* Ybf = (unsigned*)d_ws;                  // 4096*64 dwords = 1 MB
    float*    E   = (float*)(Ybf + (size_t)N_NODES * 64);  // 64 KB

    gat_proj<<<N_NODES / K1_ROWS, 256, 0, stream>>>(x, W, a, Ybf, E);
    gat_sum<<<N_NODES / 2, 256, 0, stream>>>(adj, Ybf, E, out);
}